// Round 4
// baseline (232.310 us; speedup 1.0000x reference)
//
#include <hip/hip_runtime.h>

// CapsuleLayer: B=64, L=512, D=1024, C=32, O=64, 3 routing iters.
// u_hat never materialized:
//   dots[b,l,c] = in[b,l,:]@w_v[b,c,:] + bias_v[b,c]   (w_v[b,c,d] = sum_o fc_w[d,cO+o] v[b,c,o])
//   s_j[b,c,:]  = x_c[b,c,:]@fc_w[:,c,:] + csum[b,c]*fc_b[c,:]   (x_c = sum_l c_w * in)
// All three contractions via mfma_f32_16x16x32_bf16, direct global->fragment
// loads. Layouts: in_bf[b][l][d] bf16 (route A-frags), in_T[b][d][l] bf16
// (xc B-frags), fc_wT[co][d] bf16, c_wT[b][c][l] bf16, x_cb[c][b][d] bf16.

namespace {
constexpr int Bn = 64, Ln = 512, Dn = 1024, Cn = 32, On = 64, COn = Cn * On;
}

typedef float f32x4 __attribute__((ext_vector_type(4)));
typedef short bf16x8 __attribute__((ext_vector_type(8)));

static __device__ __forceinline__ unsigned short f2bf(float f) {
    unsigned u = __float_as_uint(f);
    u += 0x7fff + ((u >> 16) & 1);   // RNE
    return (unsigned short)(u >> 16);
}

// ---------------------------------------------------------------- prep ------
// in fp32 [b][l][d] -> in_bf bf16 [b][l][d] + in_T bf16 [b][d][l]
//                    + rowsum partials [b][lc][d]
__global__ __launch_bounds__(256) void k_prep(const float* __restrict__ in,
                                              short* __restrict__ in_bf,
                                              short* __restrict__ in_T,
                                              float* __restrict__ rs_p) {
    __shared__ short tr[64 * 260];      // [l-row][d-col], pad 260 shorts
    __shared__ float4 rs4_sh[4][64];
    int b = blockIdx.y;
    int lc = blockIdx.x >> 2, dc = blockIdx.x & 3;
    int t = threadIdx.x;
    int grp = t >> 6, dq = t & 63;
    float4 rs = make_float4(0.f, 0.f, 0.f, 0.f);
    const float* src = in + ((size_t)b * Ln + lc * 64) * Dn + dc * 256 + dq * 4;
    short* dst_bf = in_bf + ((size_t)b * Ln + lc * 64) * Dn + dc * 256 + dq * 4;
#pragma unroll
    for (int i = 0; i < 16; ++i) {
        int row = grp + 4 * i;
        float4 x = *(const float4*)(src + (size_t)row * Dn);
        rs.x += x.x; rs.y += x.y; rs.z += x.z; rs.w += x.w;
        short4 s4 = make_short4((short)f2bf(x.x), (short)f2bf(x.y),
                                (short)f2bf(x.z), (short)f2bf(x.w));
        *(short4*)(&tr[row * 260 + dq * 4]) = s4;
        *(short4*)(dst_bf + (size_t)row * Dn) = s4;
    }
    rs4_sh[grp][dq] = rs;
    __syncthreads();
    if (t < 64) {
        float4 a = rs4_sh[0][t], b2 = rs4_sh[1][t], c2 = rs4_sh[2][t], d2 = rs4_sh[3][t];
        float4 s = make_float4(a.x + b2.x + c2.x + d2.x, a.y + b2.y + c2.y + d2.y,
                               a.z + b2.z + c2.z + d2.z, a.w + b2.w + c2.w + d2.w);
        *(float4*)(rs_p + ((size_t)b * 8 + lc) * Dn + dc * 256 + t * 4) = s;
    }
#pragma unroll
    for (int i = 0; i < 8; ++i) {
        int idx = t + 256 * i;
        int drow = idx >> 3, slot = idx & 7;
        bf16x8 v;
#pragma unroll
        for (int j = 0; j < 8; ++j) v[j] = tr[(slot * 8 + j) * 260 + drow];
        *(bf16x8*)(in_T + ((size_t)b * Dn + dc * 256 + drow) * Ln + lc * 64 + slot * 8) = v;
    }
}

// ---------------------------------------------------------------- wprep -----
// fc_w fp32 [d][co] -> fc_wT bf16 [co][d]
__global__ __launch_bounds__(256) void k_wprep(const float* __restrict__ fc_w,
                                               short* __restrict__ fc_wT) {
    __shared__ short tr[64 * 260];      // [d-row][co-col]
    int d0 = blockIdx.x * 64;           // 16
    int co0 = blockIdx.y * 256;         // 8
    int t = threadIdx.x, grp = t >> 6, cq = t & 63;
#pragma unroll
    for (int i = 0; i < 16; ++i) {
        int row = grp + 4 * i;
        float4 x = *(const float4*)(fc_w + (size_t)(d0 + row) * COn + co0 + cq * 4);
        *(short4*)(&tr[row * 260 + cq * 4]) =
            make_short4((short)f2bf(x.x), (short)f2bf(x.y),
                        (short)f2bf(x.z), (short)f2bf(x.w));
    }
    __syncthreads();
#pragma unroll
    for (int i = 0; i < 8; ++i) {
        int idx = t + 256 * i;
        int corow = idx >> 3, slot = idx & 7;
        bf16x8 v;
#pragma unroll
        for (int j = 0; j < 8; ++j) v[j] = tr[(slot * 8 + j) * 260 + corow];
        *(bf16x8*)(fc_wT + (size_t)(co0 + corow) * Dn + d0 + slot * 8) = v;
    }
}

// ---------------------------------------------------------------- rsred -----
__global__ __launch_bounds__(256) void k_rsred(const float* __restrict__ rs_p,
                                               unsigned short* __restrict__ rs_bf) {
    int b = blockIdx.y, d = blockIdx.x * 256 + threadIdx.x;
    float s = 0.f;
#pragma unroll
    for (int lc = 0; lc < 8; ++lc) s += rs_p[((size_t)b * 8 + lc) * Dn + d];
    rs_bf[b * Dn + d] = f2bf(s * (1.0f / 32.0f));
}

// ------------------------------------------------------- s -> squash -> v ---
// Per-c MFMA GEMM: S[64 b][64 o] = X(64x1024)@W_c(1024x64). No LDS.
__global__ __launch_bounds__(256) void k_sv3(const short* __restrict__ xA,
                                             const float* __restrict__ csum_p,
                                             const short* __restrict__ fc_wT,
                                             const float* __restrict__ fc_b,
                                             float* __restrict__ v_out,
                                             float* __restrict__ bias_v,
                                             int mode0) {
    int c = blockIdx.x;
    int t = threadIdx.x, w = t >> 6, lane = t & 63;
    int l15 = lane & 15, lg = lane >> 4;
    const short* A = mode0 ? xA : (xA + (size_t)c * Bn * Dn);   // [b][d]
    const short* Bw = fc_wT + (size_t)c * On * Dn;              // [o][d]
    f32x4 acc[4];
#pragma unroll
    for (int i = 0; i < 4; ++i) acc[i] = {0.f, 0.f, 0.f, 0.f};
    for (int ks = 0; ks < 32; ++ks) {
        int koff = ks * 32 + lg * 8;
        bf16x8 a = *(const bf16x8*)(A + (size_t)(w * 16 + l15) * Dn + koff);
#pragma unroll
        for (int dt = 0; dt < 4; ++dt) {
            bf16x8 bb = *(const bf16x8*)(Bw + (size_t)(dt * 16 + l15) * Dn + koff);
            acc[dt] = __builtin_amdgcn_mfma_f32_16x16x32_bf16(a, bb, acc[dt], 0, 0, 0);
        }
    }
    float fb[4];
#pragma unroll
    for (int dt = 0; dt < 4; ++dt) fb[dt] = fc_b[c * On + dt * 16 + l15];
#pragma unroll
    for (int r = 0; r < 4; ++r) {
        int brow = w * 16 + lg * 4 + r;
        float cs;
        if (mode0) {
            cs = 16.0f;
        } else {
            cs = 0.f;
#pragma unroll
            for (int lt = 0; lt < 8; ++lt) cs += csum_p[((size_t)lt * Bn + brow) * Cn + c];
        }
        float s0 = acc[0][r] + cs * fb[0];
        float s1 = acc[1][r] + cs * fb[1];
        float s2 = acc[2][r] + cs * fb[2];
        float s3 = acc[3][r] + cs * fb[3];
        float sq = s0 * s0 + s1 * s1 + s2 * s2 + s3 * s3;
        sq += __shfl_xor(sq, 1, 64); sq += __shfl_xor(sq, 2, 64);
        sq += __shfl_xor(sq, 4, 64); sq += __shfl_xor(sq, 8, 64);
        float scale = sq / (1.0f + sq) * rsqrtf(sq + 1e-8f);
        float v0 = scale * s0, v1 = scale * s1, v2 = scale * s2, v3 = scale * s3;
        float* vp = v_out + ((size_t)brow * Cn + c) * On;
        vp[0 * 16 + l15] = v0; vp[1 * 16 + l15] = v1;
        vp[2 * 16 + l15] = v2; vp[3 * 16 + l15] = v3;
        float bv = fb[0] * v0 + fb[1] * v1 + fb[2] * v2 + fb[3] * v3;
        bv += __shfl_xor(bv, 1, 64); bv += __shfl_xor(bv, 2, 64);
        bv += __shfl_xor(bv, 4, 64); bv += __shfl_xor(bv, 8, 64);
        if (l15 == 0) bias_v[brow * Cn + c] = bv;
    }
}

// -------------------------------------------------- w_v[b,c,d] projection ---
// fp32 math, bf16 output. grid (8 dtiles, 32 c), block 256.
__global__ __launch_bounds__(256) void k_wv2b(const float* __restrict__ v,
                                              const float* __restrict__ fc_w,
                                              short* __restrict__ w_vb) {
    int dtile = blockIdx.x;   // 0..7
    int c = blockIdx.y;       // 0..31
    int t = threadIdx.x;
    int bg = t & 7;           // b = bg + 8*bi
    int dg = t >> 3;          // d = d0 + dg*4 + dj
    __shared__ float fc_sh[128 * 68];
    __shared__ float v_sh[64 * 68];
    int d0 = dtile * 128;
#pragma unroll
    for (int i = 0; i < 8; ++i) {
        int idx = t + 256 * i;
        int dl = idx >> 4, oq = idx & 15;
        *(float4*)(fc_sh + dl * 68 + oq * 4) =
            *(const float4*)(fc_w + (size_t)(d0 + dl) * COn + c * On + oq * 4);
    }
#pragma unroll
    for (int i = 0; i < 4; ++i) {
        int idx = t + 256 * i;
        int bl = idx >> 4, oq = idx & 15;
        *(float4*)(v_sh + bl * 68 + oq * 4) =
            *(const float4*)(v + ((size_t)bl * Cn + c) * On + oq * 4);
    }
    __syncthreads();

    float acc[8][4];
#pragma unroll
    for (int i = 0; i < 8; ++i)
#pragma unroll
        for (int j = 0; j < 4; ++j) acc[i][j] = 0.f;

#pragma unroll 2
    for (int o = 0; o < 64; o += 4) {
        float4 fc4[4];
#pragma unroll
        for (int dj = 0; dj < 4; ++dj)
            fc4[dj] = *(const float4*)(fc_sh + (dg * 4 + dj) * 68 + o);
#pragma unroll
        for (int bi = 0; bi < 8; ++bi) {
            float4 v4 = *(const float4*)(v_sh + (bg + 8 * bi) * 68 + o);
#pragma unroll
            for (int dj = 0; dj < 4; ++dj) {
                acc[bi][dj] += v4.x * fc4[dj].x + v4.y * fc4[dj].y +
                               v4.z * fc4[dj].z + v4.w * fc4[dj].w;
            }
        }
    }
#pragma unroll
    for (int bi = 0; bi < 8; ++bi) {
        int b = bg + 8 * bi;
        *(short4*)(w_vb + ((size_t)b * Cn + c) * Dn + d0 + dg * 4) =
            make_short4((short)f2bf(acc[bi][0]), (short)f2bf(acc[bi][1]),
                        (short)f2bf(acc[bi][2]), (short)f2bf(acc[bi][3]));
    }
}

// ------------------------------- dots -> b_ij update -> softmax -> c_wT -----
// grid (8 lt, 64 b), 256 thr / 4 waves, wave = 16 l-rows x 32 c. MFMA,
// A-frags straight from in_bf (bf16), B = w_v bf16 rows.
__global__ __launch_bounds__(256) void k_route_m(const short* __restrict__ in_bf,
                                                 const short* __restrict__ w_v,
                                                 const float* __restrict__ bias_v,
                                                 float* __restrict__ b_ij,
                                                 short* __restrict__ c_wT,
                                                 float* __restrict__ csum_p,
                                                 int first) {
    __shared__ short cw_sh[Cn * 68];
    __shared__ float cs_sh[4][Cn];
    int lt = blockIdx.x, b = blockIdx.y;
    int t = threadIdx.x, w = t >> 6, lane = t & 63;
    int l15 = lane & 15, lg = lane >> 4;
    int l0 = lt * 64;
    f32x4 acc0 = {0.f, 0.f, 0.f, 0.f}, acc1 = {0.f, 0.f, 0.f, 0.f};
    const short* Ap = in_bf + ((size_t)b * Ln + l0 + w * 16 + l15) * Dn;
    const short* Bp = w_v + (size_t)b * Cn * Dn;
    for (int ks = 0; ks < 32; ++ks) {
        int koff = ks * 32 + lg * 8;
        bf16x8 a = *(const bf16x8*)(Ap + koff);
        bf16x8 b0 = *(const bf16x8*)(Bp + (size_t)l15 * Dn + koff);
        bf16x8 b1 = *(const bf16x8*)(Bp + (size_t)(l15 + 16) * Dn + koff);
        acc0 = __builtin_amdgcn_mfma_f32_16x16x32_bf16(a, b0, acc0, 0, 0, 0);
        acc1 = __builtin_amdgcn_mfma_f32_16x16x32_bf16(a, b1, acc1, 0, 0, 0);
    }
    float bv0 = bias_v[b * Cn + l15];
    float bv1 = bias_v[b * Cn + l15 + 16];
    float csa0 = 0.f, csa1 = 0.f;
#pragma unroll
    for (int r = 0; r < 4; ++r) {
        int lrow = l0 + w * 16 + lg * 4 + r;
        size_t boff = ((size_t)b * Ln + lrow) * Cn;
        float d0 = acc0[r] + bv0, d1 = acc1[r] + bv1;
        if (!first) { d0 += b_ij[boff + l15]; d1 += b_ij[boff + l15 + 16]; }
        b_ij[boff + l15] = d0;
        b_ij[boff + l15 + 16] = d1;
        float m = fmaxf(d0, d1);
        m = fmaxf(m, __shfl_xor(m, 1, 64)); m = fmaxf(m, __shfl_xor(m, 2, 64));
        m = fmaxf(m, __shfl_xor(m, 4, 64)); m = fmaxf(m, __shfl_xor(m, 8, 64));
        float e0 = __expf(d0 - m), e1 = __expf(d1 - m);
        float sm = e0 + e1;
        sm += __shfl_xor(sm, 1, 64); sm += __shfl_xor(sm, 2, 64);
        sm += __shfl_xor(sm, 4, 64); sm += __shfl_xor(sm, 8, 64);
        float inv = 1.0f / sm;
        float cw0 = e0 * inv, cw1 = e1 * inv;
        csa0 += cw0; csa1 += cw1;
        int ll = w * 16 + lg * 4 + r;
        cw_sh[l15 * 68 + ll] = (short)f2bf(cw0);
        cw_sh[(l15 + 16) * 68 + ll] = (short)f2bf(cw1);
    }
    csa0 += __shfl_xor(csa0, 16, 64); csa0 += __shfl_xor(csa0, 32, 64);
    csa1 += __shfl_xor(csa1, 16, 64); csa1 += __shfl_xor(csa1, 32, 64);
    if (lg == 0) { cs_sh[w][l15] = csa0; cs_sh[w][l15 + 16] = csa1; }
    __syncthreads();
    if (t < Cn) {
        float s = cs_sh[0][t] + cs_sh[1][t] + cs_sh[2][t] + cs_sh[3][t];
        csum_p[((size_t)lt * Bn + b) * Cn + t] = s;
    }
    {
        int cc = t >> 3, slot = t & 7;
        bf16x8 vv;
#pragma unroll
        for (int j = 0; j < 8; ++j) vv[j] = cw_sh[cc * 68 + slot * 8 + j];
        *(bf16x8*)(c_wT + ((size_t)b * Cn + cc) * Ln + l0 + slot * 8) = vv;
    }
}

// ----------------------------------------- x_cb[c][b][d] = c_w^T @ in -------
// grid (8 dt, 64 b), 256 thr / 4 waves; wave covers 32 d (2 x 16).
__global__ __launch_bounds__(256) void k_xc_m(const short* __restrict__ in_T,
                                              const short* __restrict__ c_wT,
                                              short* __restrict__ x_cb) {
    int dt = blockIdx.x, b = blockIdx.y;
    int t = threadIdx.x, w = t >> 6, lane = t & 63;
    int l15 = lane & 15, lg = lane >> 4;
    f32x4 acc[2][2];
#pragma unroll
    for (int h = 0; h < 2; ++h)
#pragma unroll
        for (int dd = 0; dd < 2; ++dd) acc[h][dd] = {0.f, 0.f, 0.f, 0.f};
    const short* A = c_wT + (size_t)b * Cn * Ln;                        // [c][l]
    const short* Bp = in_T + ((size_t)b * Dn + dt * 128 + w * 32) * Ln; // [d][l]
    for (int ks = 0; ks < 16; ++ks) {
        int koff = ks * 32 + lg * 8;
        bf16x8 a0 = *(const bf16x8*)(A + (size_t)l15 * Ln + koff);
        bf16x8 a1 = *(const bf16x8*)(A + (size_t)(l15 + 16) * Ln + koff);
#pragma unroll
        for (int dd = 0; dd < 2; ++dd) {
            bf16x8 bb = *(const bf16x8*)(Bp + (size_t)(dd * 16 + l15) * Ln + koff);
            acc[0][dd] = __builtin_amdgcn_mfma_f32_16x16x32_bf16(a0, bb, acc[0][dd], 0, 0, 0);
            acc[1][dd] = __builtin_amdgcn_mfma_f32_16x16x32_bf16(a1, bb, acc[1][dd], 0, 0, 0);
        }
    }
#pragma unroll
    for (int h = 0; h < 2; ++h)
#pragma unroll
        for (int dd = 0; dd < 2; ++dd)
#pragma unroll
            for (int r = 0; r < 4; ++r) {
                int c = 16 * h + lg * 4 + r;
                int d = dt * 128 + w * 32 + dd * 16 + l15;
                x_cb[((size_t)c * Bn + b) * Dn + d] = (short)f2bf(acc[h][dd][r]);
            }
}

// ---------------------------------------------------------------------------
extern "C" void kernel_launch(void* const* d_in, const int* in_sizes, int n_in,
                              void* d_out, int out_size, void* d_ws, size_t ws_size,
                              hipStream_t stream) {
    const float* in   = (const float*)d_in[0];
    const float* fc_w = (const float*)d_in[1];
    const float* fc_b = (const float*)d_in[2];
    float* out = (float*)d_out;

    char* p = (char*)d_ws;
    auto alloc = [&](size_t bytes) -> char* {
        char* r = p;
        p += (bytes + 255) & ~(size_t)255;
        return r;
    };
    short* in_bf  = (short*)alloc((size_t)Bn * Ln * Dn * 2);   // 64 MB
    short* in_T   = (short*)alloc((size_t)Bn * Dn * Ln * 2);   // 64 MB
    short* fc_wT  = (short*)alloc((size_t)COn * Dn * 2);       // 4 MB
    short* w_vb   = (short*)alloc((size_t)Bn * Cn * Dn * 2);   // 4 MB
    short* c_wT   = (short*)alloc((size_t)Bn * Cn * Ln * 2);   // 2 MB
    short* x_cb   = (short*)alloc((size_t)Cn * Bn * Dn * 2);   // 4 MB
    float* rs_p   = (float*)alloc((size_t)Bn * 8 * Dn * 4);    // 2 MB
    unsigned short* rs_bf = (unsigned short*)alloc((size_t)Bn * Dn * 2);
    float* b_ij   = (float*)alloc((size_t)Bn * Ln * Cn * 4);   // 4 MB
    float* v      = (float*)alloc((size_t)Bn * Cn * On * 4);
    float* bias_v = (float*)alloc((size_t)Bn * Cn * 4);
    float* csum_p = (float*)alloc((size_t)8 * Bn * Cn * 4);

    k_prep<<<dim3(32, Bn), 256, 0, stream>>>(in, in_bf, in_T, rs_p);
    k_wprep<<<dim3(16, 8), 256, 0, stream>>>(fc_w, fc_wT);
    k_rsred<<<dim3(4, Bn), 256, 0, stream>>>(rs_p, rs_bf);
    k_sv3<<<Cn, 256, 0, stream>>>((const short*)rs_bf, csum_p, fc_wT, fc_b,
                                  v, bias_v, 1);
    for (int it = 1; it <= 2; ++it) {
        k_wv2b<<<dim3(8, Cn), 256, 0, stream>>>(v, fc_w, w_vb);
        k_route_m<<<dim3(8, Bn), 256, 0, stream>>>(in_bf, w_vb, bias_v, b_ij,
                                                   c_wT, csum_p, (it == 1) ? 1 : 0);
        k_xc_m<<<dim3(8, Bn), 256, 0, stream>>>(in_T, c_wT, x_cb);
        float* vout = (it == 2) ? out : v;
        k_sv3<<<Cn, 256, 0, stream>>>(x_cb, csum_p, fc_wT, fc_b, vout, bias_v, 0);
    }
}